// Round 2
// baseline (590.374 us; speedup 1.0000x reference)
//
#include <hip/hip_runtime.h>
#include <hip/hip_bf16.h>

// BasicGCN: out = log_softmax( A @ (relu(A @ x @ W1 + b1) @ W2) + b2 )
// R10: aggregation kernels restructured to ONE NODE PER WAVE.
//  - k_agg1: 4 edges in flight via 16-lane quarters (each quarter owns one
//    edge; lane l16 owns 16 cols), unroll 4 (16 edges/iter). Cross-quarter
//    __shfl_xor(16/32) reduce at the end. Kills (a) the 47% occupancy tail
//    (25k long waves -> 100k short waves) and (b) max-of-4-degree lane
//    divergence of R9.
//  - k_agg2: same treatment, 8 edges via 8-lane octets, unroll 2; tq now
//    stored +128-biased u8 so converts are single-op v_cvt_f32_ubyteN with
//    a -128*wsum correction (same trick as agg1).

typedef __bf16 bf16;
typedef bf16 bf16x4 __attribute__((ext_vector_type(4)));
typedef bf16 bf16x8 __attribute__((ext_vector_type(8)));
typedef float f32x4 __attribute__((ext_vector_type(4)));
typedef signed char s8;

#define NBLK 256  // edge-chunk blocks for bucketing passes

// ---------------- pass 1: per-block bucket histogram (LDS) ----------------
__global__ __launch_bounds__(256) void k_b1(const int* __restrict__ edge, int E, int chunk,
                                            int NB, int* __restrict__ gcnt) {
    __shared__ int cnt[512];
    int tid = threadIdx.x;
    for (int i = tid; i < NB; i += 256) cnt[i] = 0;
    __syncthreads();
    int s = blockIdx.x * chunk, e = min(s + chunk, E);
    for (int i = s + tid; i < e; i += 256) atomicAdd(&cnt[edge[E + i] >> 9], 1);
    __syncthreads();
    for (int i = tid; i < NB; i += 256) gcnt[blockIdx.x * NB + i] = cnt[i];
}

// ---------------- pass 2a: bucket starts ----------------
__global__ void k_b2(const int* __restrict__ gcnt, int NB, int E, int* __restrict__ bstart) {
    __shared__ int col[256];
    int k = threadIdx.x;
    int sum = 0;
    if (k < NB)
        for (int b = 0; b < NBLK; ++b) sum += gcnt[b * NB + k];
    col[k] = sum;
    __syncthreads();
    for (int o = 1; o < 256; o <<= 1) {
        int v = (k >= o) ? col[k - o] : 0;
        __syncthreads();
        col[k] += v;
        __syncthreads();
    }
    if (k < NB) bstart[k] = col[k] - sum;
    if (k == 0) bstart[NB] = E;
}

// ---------------- pass 2b: per-(block,bucket) bases ----------------
__global__ void k_b2b(int* __restrict__ gcnt, int NB, const int* __restrict__ bstart) {
    __shared__ int col[256];
    int b = threadIdx.x;  // NBLK == 256
    int k = blockIdx.x;
    int v = gcnt[b * NB + k];
    col[b] = v;
    __syncthreads();
    for (int o = 1; o < 256; o <<= 1) {
        int t = (b >= o) ? col[b - o] : 0;
        __syncthreads();
        col[b] += t;
        __syncthreads();
    }
    gcnt[b * NB + k] = bstart[k] + col[b] - v;
}

// ---------------- pass 3: scatter edges into bucket-grouped ebuf ----------------
// packed: src (17 bits) | (dst & 511) << 17
__global__ __launch_bounds__(256) void k_b3(const int* __restrict__ edge, int E, int chunk,
                                            int NB, const int* __restrict__ base,
                                            int* __restrict__ ebuf) {
    __shared__ int cnt[512];
    __shared__ int bs[512];
    int tid = threadIdx.x;
    for (int i = tid; i < NB; i += 256) {
        cnt[i] = 0;
        bs[i] = base[blockIdx.x * NB + i];
    }
    __syncthreads();
    int s = blockIdx.x * chunk, e = min(s + chunk, E);
    for (int i = s + tid; i < e; i += 256) {
        int sv = edge[i], dv = edge[E + i];
        int k = dv >> 9;
        int r = atomicAdd(&cnt[k], 1);  // LDS atomic
        ebuf[bs[k] + r] = sv | ((dv & 511) << 17);
    }
}

// ---------------- pass 4+5 merged: per-bucket hist + local scan -> off, dinv ----------------
// off[node] = bstart[bucket] + exclusive_scan_within_bucket(deg)
__global__ __launch_bounds__(256) void k_b45(const int* __restrict__ ebuf,
                                             const int* __restrict__ bstart, int n, int E,
                                             int NB, int* __restrict__ off,
                                             float* __restrict__ dinv) {
    __shared__ int cnt[512];
    __shared__ int red[256];
    int tid = threadIdx.x;
    int k = blockIdx.x;
    cnt[tid] = 0;
    cnt[tid + 256] = 0;
    __syncthreads();
    int s = bstart[k], e = bstart[k + 1];
    for (int i = s + tid; i < e; i += 256) atomicAdd(&cnt[(ebuf[i] >> 17) & 511], 1);
    __syncthreads();
    int c0 = cnt[tid * 2], c1 = cnt[tid * 2 + 1];
    int sum = c0 + c1;
    red[tid] = sum;
    __syncthreads();
    for (int o = 1; o < 256; o <<= 1) {
        int v = (tid >= o) ? red[tid - o] : 0;
        __syncthreads();
        red[tid] += v;
        __syncthreads();
    }
    int ex = red[tid] - sum;  // exclusive prefix over pairs
    int base = k << 9;
    int g0 = base + tid * 2, g1 = g0 + 1;
    int o0 = s + ex, o1 = s + ex + c0;
    if (g0 < n) { off[g0] = o0; dinv[g0] = rsqrtf((float)(c0 + 1)); }
    else if (g0 == n) off[g0] = o0;
    if (g1 < n) { off[g1] = o1; dinv[g1] = rsqrtf((float)(c1 + 1)); }
    else if (g1 == n) off[g1] = o1;
    if (k == NB - 1 && tid == 0) off[n] = E;
}

// ---------------- pass 6: per-bucket CSR fill (LDS ranks, LDS off) ----------------
// pair.y = dinv[src]*scale[src] (scale folded in; k_quant runs before this)
__global__ __launch_bounds__(256) void k_b6(const int* __restrict__ ebuf,
                                            const int* __restrict__ bstart,
                                            const int* __restrict__ off,
                                            const float* __restrict__ dinv,
                                            const float* __restrict__ scale, int n,
                                            int2* __restrict__ pair) {
    __shared__ int cnt[512];
    __shared__ int offl[512];
    int tid = threadIdx.x;
    int k = blockIdx.x;
    int base = k << 9;
    cnt[tid] = 0;
    cnt[tid + 256] = 0;
    offl[tid] = (base + tid < n) ? off[base + tid] : 0;
    offl[tid + 256] = (base + 256 + tid < n) ? off[base + 256 + tid] : 0;
    __syncthreads();
    int s = bstart[k], e = bstart[k + 1];
    for (int i = s + tid; i < e; i += 256) {
        int pk = ebuf[i];
        int sv = pk & 0x1ffff;
        int node = (pk >> 17) & 511;
        int r = atomicAdd(&cnt[node], 1);  // LDS atomic
        float w = dinv[sv] * scale[sv];
        pair[offl[node] + r] = make_int2(sv, __float_as_int(w));
    }
}

// ---------------- x -> per-row-scaled biased-u8 (one wave per row) ----------------
// stored byte = round(x*127/max)+128  (unsigned, so agg converts via v_cvt_f32_ubyteN)
__global__ __launch_bounds__(256) void k_quant(const float* __restrict__ x,
                                               unsigned char* __restrict__ xq,
                                               float* __restrict__ scale, int n) {
    int row = blockIdx.x * 4 + (threadIdx.x >> 6);
    int lane = threadIdx.x & 63;
    if (row >= n) return;
    f32x4 v = ((const f32x4*)x)[(size_t)row * 64 + lane];
    float m = fmaxf(fmaxf(fabsf(v[0]), fabsf(v[1])), fmaxf(fabsf(v[2]), fabsf(v[3])));
    for (int o = 32; o > 0; o >>= 1) m = fmaxf(m, __shfl_xor(m, o));
    m = fmaxf(m, 1e-20f);
    float inv = 127.0f / m;
    int b0 = (__float2int_rn(v[0] * inv) + 128) & 255;
    int b1 = (__float2int_rn(v[1] * inv) + 128) & 255;
    int b2 = (__float2int_rn(v[2] * inv) + 128) & 255;
    int b3 = (__float2int_rn(v[3] * inv) + 128) & 255;
    ((int*)xq)[(size_t)row * 64 + lane] = b0 | (b1 << 8) | (b2 << 16) | (b3 << 24);
    if (lane == 0) scale[row] = m / 127.0f;
}

// ---------------- tb (n x 64 bf16) -> per-row biased-u8 + scale + r2 ----------------
__global__ __launch_bounds__(256) void k_quant2(const bf16* __restrict__ tb,
                                                const float* __restrict__ scale,
                                                unsigned char* __restrict__ tq,
                                                float* __restrict__ tscale,
                                                float* __restrict__ r2, int n) {
    int t = blockIdx.x * 256 + threadIdx.x;
    int row = t >> 3;
    int l8 = t & 7;
    if (row >= n) return;
    bf16x8 v = ((const bf16x8*)tb)[(size_t)row * 8 + l8];
    float f[8], m = 0.0f;
#pragma unroll
    for (int j = 0; j < 8; ++j) { f[j] = (float)v[j]; m = fmaxf(m, fabsf(f[j])); }
    for (int o = 4; o > 0; o >>= 1) m = fmaxf(m, __shfl_xor(m, o));
    m = fmaxf(m, 1e-20f);
    float inv = 127.0f / m;
    int lo = 0, hi = 0;
#pragma unroll
    for (int j = 0; j < 4; ++j) lo |= ((__float2int_rn(f[j] * inv) + 128) & 255) << (8 * j);
#pragma unroll
    for (int j = 0; j < 4; ++j) hi |= ((__float2int_rn(f[4 + j] * inv) + 128) & 255) << (8 * j);
    ((int2*)tq)[(size_t)row * 8 + l8] = make_int2(lo, hi);
    if (l8 == 0) {
        float s = m / 127.0f;
        tscale[row] = s;
        r2[row] = s / scale[row];  // pair.y * r2[src] == dinv[src]*tscale[src]
    }
}

// ---------------- W (KxNC fp32) -> Wt (NCxK bf16) ----------------
__global__ void k_wt(const float* __restrict__ W, bf16* __restrict__ Wt, int NC) {
    int nc = blockIdx.x;
    int k = threadIdx.x;
    Wt[nc * 256 + k] = (bf16)W[k * NC + nc];
}

// accumulate 16 biased-u8 elements: a[j] += w*u[j]; wsum += w
// (float)((u>>8)&255) etc. lower to single v_cvt_f32_ubyte{0..3}
__device__ __forceinline__ void acc16(float a[16], uint4 t, float w, float& wsum) {
    wsum += w;
    unsigned u0 = t.x, u1 = t.y, u2 = t.z, u3 = t.w;
    a[0]  += w * (float)(u0 & 255u);
    a[1]  += w * (float)((u0 >> 8) & 255u);
    a[2]  += w * (float)((u0 >> 16) & 255u);
    a[3]  += w * (float)(u0 >> 24);
    a[4]  += w * (float)(u1 & 255u);
    a[5]  += w * (float)((u1 >> 8) & 255u);
    a[6]  += w * (float)((u1 >> 16) & 255u);
    a[7]  += w * (float)(u1 >> 24);
    a[8]  += w * (float)(u2 & 255u);
    a[9]  += w * (float)((u2 >> 8) & 255u);
    a[10] += w * (float)((u2 >> 16) & 255u);
    a[11] += w * (float)(u2 >> 24);
    a[12] += w * (float)(u3 & 255u);
    a[13] += w * (float)((u3 >> 8) & 255u);
    a[14] += w * (float)((u3 >> 16) & 255u);
    a[15] += w * (float)(u3 >> 24);
}

// accumulate 8 biased-u8 elements from int2
__device__ __forceinline__ void acc8(float a[8], int2 t, float w, float& wsum) {
    wsum += w;
    unsigned u0 = (unsigned)t.x, u1 = (unsigned)t.y;
    a[0] += w * (float)(u0 & 255u);
    a[1] += w * (float)((u0 >> 8) & 255u);
    a[2] += w * (float)((u0 >> 16) & 255u);
    a[3] += w * (float)(u0 >> 24);
    a[4] += w * (float)(u1 & 255u);
    a[5] += w * (float)((u1 >> 8) & 255u);
    a[6] += w * (float)((u1 >> 16) & 255u);
    a[7] += w * (float)(u1 >> 24);
}

// ---------------- agg1: ax = A @ x. ONE NODE PER WAVE ----------------
// 16-lane quarter q owns edge e+4i+q; lane l16 owns cols l16*16..+16.
// Cross-quarter reduce via shfl_xor(16/32) at the end.
__global__ __launch_bounds__(256) void k_agg1(const unsigned char* __restrict__ xq,
                                              const float* __restrict__ scale,
                                              const int* __restrict__ off,
                                              const int2* __restrict__ pair,
                                              const float* __restrict__ dinv,
                                              bf16* __restrict__ ax, int n) {
    int node = blockIdx.x * 4 + (threadIdx.x >> 6);
    int lane = threadIdx.x & 63;
    int qt = lane >> 4;
    int l16 = lane & 15;
    if (node >= n) return;
    int s0 = off[node], s1 = off[node + 1];
    float dv = dinv[node];
    float a[16] = {};
    float wsum = 0.0f;
    // self loop: quarter 0 only (others contribute w=0)
    uint4 xs = *(const uint4*)(xq + (size_t)node * 256 + l16 * 16);
    acc16(a, xs, (qt == 0) ? dv * scale[node] : 0.0f, wsum);
    int e = s0;
    for (; e + 16 <= s1; e += 16) {
        int2 p[4];
#pragma unroll
        for (int i = 0; i < 4; ++i) p[i] = pair[e + 4 * i + qt];
        uint4 t[4];
#pragma unroll
        for (int i = 0; i < 4; ++i)
            t[i] = *(const uint4*)(xq + (size_t)p[i].x * 256 + l16 * 16);
#pragma unroll
        for (int i = 0; i < 4; ++i) acc16(a, t[i], __int_as_float(p[i].y), wsum);
    }
    for (; e < s1; e += 4) {
        int idx = e + qt;
        bool on = idx < s1;
        int2 p = pair[on ? idx : s0];
        uint4 t = *(const uint4*)(xq + (size_t)p.x * 256 + l16 * 16);
        acc16(a, t, on ? __int_as_float(p.y) : 0.0f, wsum);
    }
    // reduce across quarters (lanes ^16, ^32)
#pragma unroll
    for (int j = 0; j < 16; ++j) {
        a[j] += __shfl_xor(a[j], 16);
        a[j] += __shfl_xor(a[j], 32);
    }
    wsum += __shfl_xor(wsum, 16);
    wsum += __shfl_xor(wsum, 32);
    float c = 128.0f * wsum;  // undo the +128 bias
    if (qt == 0) {
        bf16x8 o0, o1;
#pragma unroll
        for (int j = 0; j < 8; ++j) o0[j] = (bf16)((a[j] - c) * dv);
#pragma unroll
        for (int j = 0; j < 8; ++j) o1[j] = (bf16)((a[8 + j] - c) * dv);
        ((bf16x8*)ax)[(size_t)node * 32 + l16 * 2] = o0;
        ((bf16x8*)ax)[(size_t)node * 32 + l16 * 2 + 1] = o1;
    }
}

// ---------------- row-panel GEMM (layer 1): C[n x 256] = A[n x 256] @ Bt^T, +bias+relu ----
// 64-row panel per block; A read once; per wave: 16 col-tiles, 17 ds_read : 16 MFMA.
__global__ __launch_bounds__(256) void k_gemmp(const bf16* __restrict__ A,
                                               const bf16* __restrict__ Bt,
                                               const float* __restrict__ bias,
                                               bf16* __restrict__ C, int n) {
    __shared__ __align__(16) bf16 As[4 * 64 * 8];    // 64 rows x 32 k
    __shared__ __align__(16) bf16 Bs[16 * 64 * 8];   // 256 N x 32 k
    int tid = threadIdx.x;
    int bm = blockIdx.x * 64;
    int w = tid >> 6, lane = tid & 63;

    int r = tid >> 2;
    int cq = tid & 3;
    int a_idx = (((r >> 4) * 64) + cq * 16 + (r & 15)) * 8;
    int arow = bm + r; if (arow > n - 1) arow = n - 1;

    f32x4 acc[16] = {};

    for (int k0 = 0; k0 < 256; k0 += 32) {
        __syncthreads();
        uint4 av = *(const uint4*)(A + (size_t)arow * 256 + k0 + cq * 8);
        *(uint4*)(As + a_idx) = av;
#pragma unroll
        for (int rep = 0; rep < 4; ++rep) {
            int r2 = rep * 64 + r;
            uint4 bv = *(const uint4*)(Bt + (size_t)r2 * 256 + k0 + cq * 8);
            *(uint4*)(Bs + (((r2 >> 4) * 64) + cq * 16 + (r2 & 15)) * 8) = bv;
        }
        __syncthreads();
        bf16x8 af = *(const bf16x8*)(As + (w * 64 + lane) * 8);
#pragma unroll
        for (int ct = 0; ct < 16; ++ct) {
            bf16x8 bfr = *(const bf16x8*)(Bs + (ct * 64 + lane) * 8);
            acc[ct] = __builtin_amdgcn_mfma_f32_16x16x32_bf16(af, bfr, acc[ct], 0, 0, 0);
        }
    }

    int colb = lane & 15, rowq = lane >> 4;
#pragma unroll
    for (int ct = 0; ct < 16; ++ct) {
        int col = ct * 16 + colb;
        float bv = bias[col];
#pragma unroll
        for (int rr = 0; rr < 4; ++rr) {
            int row = bm + w * 16 + rowq * 4 + rr;
            if (row < n) {
                float v = acc[ct][rr] + bv;
                C[(size_t)row * 256 + col] = (bf16)(v > 0.0f ? v : 0.0f);
            }
        }
    }
}

// ---------------- 64x64 GEMM (layer 2): C[n x 64] = A[n x 256] @ Bt[64 x 256]^T ----------------
__global__ __launch_bounds__(256) void k_gemm2(const bf16* __restrict__ A,
                                               const bf16* __restrict__ Bt,
                                               bf16* __restrict__ C, int n) {
    __shared__ __align__(16) bf16 As[4 * 64 * 8];
    __shared__ __align__(16) bf16 Bs[4 * 64 * 8];
    int tid = threadIdx.x;
    int bm = blockIdx.x * 64;
    int w = tid >> 6, lane = tid & 63;
    int wm = w >> 1, wn = w & 1;

    int r = tid >> 2;
    int cq = tid & 3;
    int lds_idx = (((r >> 4) * 64) + cq * 16 + (r & 15)) * 8;
    int arow = bm + r; if (arow > n - 1) arow = n - 1;

    f32x4 acc[2][2] = {};

    for (int k0 = 0; k0 < 256; k0 += 32) {
        __syncthreads();
        uint4 av = *(const uint4*)(A + (size_t)arow * 256 + k0 + cq * 8);
        uint4 bv = *(const uint4*)(Bt + (size_t)r * 256 + k0 + cq * 8);
        *(uint4*)(As + lds_idx) = av;
        *(uint4*)(Bs + lds_idx) = bv;
        __syncthreads();
#pragma unroll
        for (int i = 0; i < 2; ++i) {
            bf16x8 af = *(const bf16x8*)(As + ((wm * 2 + i) * 64 + lane) * 8);
#pragma unroll
            for (int j = 0; j < 2; ++j) {
                bf16x8 bfr = *(const bf16x8*)(Bs + ((wn * 2 + j) * 64 + lane) * 8);
                acc[i][j] = __builtin_amdgcn_mfma_f32_16x16x32_bf16(af, bfr, acc[i][j], 0, 0, 0);
            }
        }
    }

    int colb = lane & 15, rowq = lane >> 4;
#pragma unroll
    for (int i = 0; i < 2; ++i) {
#pragma unroll
        for (int j = 0; j < 2; ++j) {
            int col = wn * 32 + j * 16 + colb;
#pragma unroll
            for (int rr = 0; rr < 4; ++rr) {
                int row = bm + wm * 32 + i * 16 + rowq * 4 + rr;
                if (row < n) C[(size_t)row * 64 + col] = (bf16)acc[i][j][rr];
            }
        }
    }
}

// ---------------- agg2 + bias + log_softmax. ONE NODE PER WAVE ----------------
// 8-lane octet o owns edge e+8i+o; lane l8 owns cols l8*8..+8.
// per-edge weight = pair.y * r2[src] == dinv[src]*tscale[src]
__global__ __launch_bounds__(256) void k_agg2(const unsigned char* __restrict__ tq,
                                              const float* __restrict__ tscale,
                                              const float* __restrict__ r2,
                                              const int* __restrict__ off,
                                              const int2* __restrict__ pair,
                                              const float* __restrict__ dinv,
                                              const float* __restrict__ b2,
                                              float* __restrict__ out, int n) {
    int node = blockIdx.x * 4 + (threadIdx.x >> 6);
    int lane = threadIdx.x & 63;
    int oct = lane >> 3;
    int l8 = lane & 7;
    if (node >= n) return;
    int s0 = off[node], s1 = off[node + 1];
    float dv = dinv[node];
    const int2* T = (const int2*)tq;  // row = 8 x int2 (64B)
    float a[8] = {};
    float wsum = 0.0f;
    // self loop: octet 0 only
    int2 ts = T[(size_t)node * 8 + l8];
    acc8(a, ts, (oct == 0) ? dv * tscale[node] : 0.0f, wsum);
    int e = s0;
    for (; e + 16 <= s1; e += 16) {
        int2 p0 = pair[e + oct], p1 = pair[e + 8 + oct];
        float sc0 = r2[p0.x], sc1 = r2[p1.x];
        int2 t0 = T[(size_t)p0.x * 8 + l8];
        int2 t1 = T[(size_t)p1.x * 8 + l8];
        acc8(a, t0, __int_as_float(p0.y) * sc0, wsum);
        acc8(a, t1, __int_as_float(p1.y) * sc1, wsum);
    }
    for (; e < s1; e += 8) {
        int idx = e + oct;
        bool on = idx < s1;
        int2 p = pair[on ? idx : s0];
        float w = on ? __int_as_float(p.y) * r2[p.x] : 0.0f;
        int2 t = T[(size_t)p.x * 8 + l8];
        acc8(a, t, w, wsum);
    }
    // reduce across octets (lanes ^8, ^16, ^32)
#pragma unroll
    for (int j = 0; j < 8; ++j) {
        a[j] += __shfl_xor(a[j], 8);
        a[j] += __shfl_xor(a[j], 16);
        a[j] += __shfl_xor(a[j], 32);
    }
    wsum += __shfl_xor(wsum, 8);
    wsum += __shfl_xor(wsum, 16);
    wsum += __shfl_xor(wsum, 32);
    float c = 128.0f * wsum;  // undo the +128 bias
    const float4* B2 = (const float4*)b2;
    float4 bv0 = B2[l8 * 2], bv1 = B2[l8 * 2 + 1];
    a[0] = (a[0] - c) * dv + bv0.x; a[1] = (a[1] - c) * dv + bv0.y;
    a[2] = (a[2] - c) * dv + bv0.z; a[3] = (a[3] - c) * dv + bv0.w;
    a[4] = (a[4] - c) * dv + bv1.x; a[5] = (a[5] - c) * dv + bv1.y;
    a[6] = (a[6] - c) * dv + bv1.z; a[7] = (a[7] - c) * dv + bv1.w;
    float m = a[0];
#pragma unroll
    for (int j = 1; j < 8; ++j) m = fmaxf(m, a[j]);
    for (int o = 4; o > 0; o >>= 1) m = fmaxf(m, __shfl_xor(m, o));
    float s = 0.0f;
#pragma unroll
    for (int j = 0; j < 8; ++j) s += __expf(a[j] - m);
    for (int o = 4; o > 0; o >>= 1) s += __shfl_xor(s, o);
    float ls = m + __logf(s);
    if (oct == 0) {
        f32x4 o0, o1;
        o0[0] = a[0] - ls; o0[1] = a[1] - ls; o0[2] = a[2] - ls; o0[3] = a[3] - ls;
        o1[0] = a[4] - ls; o1[1] = a[5] - ls; o1[2] = a[6] - ls; o1[3] = a[7] - ls;
        f32x4* O = (f32x4*)out;  // row = 16 x f32x4
        O[(size_t)node * 16 + l8 * 2] = o0;
        O[(size_t)node * 16 + l8 * 2 + 1] = o1;
    }
}

extern "C" void kernel_launch(void* const* d_in, const int* in_sizes, int n_in,
                              void* d_out, int out_size, void* d_ws, size_t ws_size,
                              hipStream_t stream) {
    const float* x   = (const float*)d_in[0];
    const int*  edge = (const int*)d_in[1];
    const float* W1  = (const float*)d_in[2];
    const float* b1  = (const float*)d_in[3];
    const float* W2  = (const float*)d_in[4];
    const float* b2  = (const float*)d_in[5];
    float* out = (float*)d_out;

    int n = in_sizes[0] / 256;   // 100000
    int E = in_sizes[1] / 2;     // 3200000
    int NB = (n + 511) >> 9;     // node buckets (512 each); requires n < 131072
    int chunk = (E + NBLK - 1) / NBLK;

    char* ws = (char*)d_ws;
    auto alloc = [&](size_t bytes) -> char* {
        char* p = ws;
        ws += (bytes + 255) & ~(size_t)255;
        return p;
    };
    int*   gcnt   = (int*)alloc((size_t)NBLK * NB * 4);
    int*   bstart = (int*)alloc((size_t)(NB + 1) * 4);
    int*   ebuf   = (int*)alloc((size_t)E * 4);
    float* dinv   = (float*)alloc((size_t)n * 4);
    int*   off    = (int*)alloc((size_t)(n + 1) * 4);
    int2*  pair   = (int2*)alloc((size_t)E * 8);
    unsigned char* xq = (unsigned char*)alloc((size_t)n * 256);
    float* scale  = (float*)alloc((size_t)n * 4);
    bf16*  ax     = (bf16*)alloc((size_t)n * 256 * 2);
    bf16*  h1     = (bf16*)alloc((size_t)n * 256 * 2);
    bf16*  tb     = (bf16*)alloc((size_t)n * 64 * 2);
    unsigned char* tq = (unsigned char*)alloc((size_t)n * 64);
    float* tscale = (float*)alloc((size_t)n * 4);
    float* r2     = (float*)alloc((size_t)n * 4);
    bf16*  W1t    = (bf16*)alloc(256 * 256 * 2);
    bf16*  W2t    = (bf16*)alloc(64 * 256 * 2);

    // --- feature quant first (k_b6 folds scale into pair.y) ---
    k_quant<<<(n + 3) / 4, 256, 0, stream>>>(x, xq, scale, n);

    // --- CSR build (no global atomics) ---
    k_b1<<<NBLK, 256, 0, stream>>>(edge, E, chunk, NB, gcnt);
    k_b2<<<1, 256, 0, stream>>>(gcnt, NB, E, bstart);
    k_b2b<<<NB, 256, 0, stream>>>(gcnt, NB, bstart);
    k_b3<<<NBLK, 256, 0, stream>>>(edge, E, chunk, NB, gcnt, ebuf);
    k_b45<<<NB, 256, 0, stream>>>(ebuf, bstart, n, E, NB, off, dinv);
    k_b6<<<NB, 256, 0, stream>>>(ebuf, bstart, off, dinv, scale, n, pair);

    // --- weights ---
    k_wt<<<256, 256, 0, stream>>>(W1, W1t, 256);
    k_wt<<<64, 256, 0, stream>>>(W2, W2t, 64);

    // --- layer 1 ---
    k_agg1<<<(n + 3) / 4, 256, 0, stream>>>(xq, scale, off, pair, dinv, ax, n);
    k_gemmp<<<(n + 63) / 64, 256, 0, stream>>>(ax, W1t, b1, h1, n);

    // --- layer 2 ---
    k_gemm2<<<(n + 63) / 64, 256, 0, stream>>>(h1, W2t, tb, n);
    k_quant2<<<(n * 8 + 255) / 256, 256, 0, stream>>>(tb, scale, tq, tscale, r2, n);
    k_agg2<<<(n + 3) / 4, 256, 0, stream>>>(tq, tscale, r2, off, pair, dinv, b2, out, n);
}

// Round 3
// 543.808 us; speedup vs baseline: 1.0856x; 1.0856x over previous
//
#include <hip/hip_runtime.h>
#include <hip/hip_bf16.h>

// BasicGCN: out = log_softmax( A @ (relu(A @ x @ W1 + b1) @ W2) + b2 )
// R11: revert aggs to the best-measured R9/R8 shapes, then attack latency:
//  - k_agg1: R9 structure (4 nodes/wave, 16 lanes/node, 16B/lane, unroll 4)
//    + software-rotated pair prefetch (next iter's pairs load under current
//    iter's gathers/FMAs) — pair-load latency off the critical path.
//  - k_agg2: R8 structure (8 nodes/wave, 8 lanes/node) + biased-u8 convert
//    (v_cvt_f32_ubyteN) + same rotation.
//  - k_b45 emits ws = dinv*scale (coalesced); k_b6 gathers only ws[sv]
//    (same gather count as R8's b6, keeps R9's lighter agg1).
//  - k_gemmp/k_gemm2: LDS slot XOR-swizzle (slot^=(slot>>3)&7, 16B units)
//    kills the 8-way bank conflict on fragment ds_read_b128 (lane stride
//    16B put 8 lanes/bank); store and read patterns both conflict-free.

typedef __bf16 bf16;
typedef bf16 bf16x4 __attribute__((ext_vector_type(4)));
typedef bf16 bf16x8 __attribute__((ext_vector_type(8)));
typedef float f32x4 __attribute__((ext_vector_type(4)));
typedef signed char s8;

#define NBLK 256  // edge-chunk blocks for bucketing passes

// ---------------- pass 1: per-block bucket histogram (LDS) ----------------
__global__ __launch_bounds__(256) void k_b1(const int* __restrict__ edge, int E, int chunk,
                                            int NB, int* __restrict__ gcnt) {
    __shared__ int cnt[512];
    int tid = threadIdx.x;
    for (int i = tid; i < NB; i += 256) cnt[i] = 0;
    __syncthreads();
    int s = blockIdx.x * chunk, e = min(s + chunk, E);
    for (int i = s + tid; i < e; i += 256) atomicAdd(&cnt[edge[E + i] >> 9], 1);
    __syncthreads();
    for (int i = tid; i < NB; i += 256) gcnt[blockIdx.x * NB + i] = cnt[i];
}

// ---------------- pass 2a: bucket starts ----------------
__global__ void k_b2(const int* __restrict__ gcnt, int NB, int E, int* __restrict__ bstart) {
    __shared__ int col[256];
    int k = threadIdx.x;
    int sum = 0;
    if (k < NB)
        for (int b = 0; b < NBLK; ++b) sum += gcnt[b * NB + k];
    col[k] = sum;
    __syncthreads();
    for (int o = 1; o < 256; o <<= 1) {
        int v = (k >= o) ? col[k - o] : 0;
        __syncthreads();
        col[k] += v;
        __syncthreads();
    }
    if (k < NB) bstart[k] = col[k] - sum;
    if (k == 0) bstart[NB] = E;
}

// ---------------- pass 2b: per-(block,bucket) bases ----------------
__global__ void k_b2b(int* __restrict__ gcnt, int NB, const int* __restrict__ bstart) {
    __shared__ int col[256];
    int b = threadIdx.x;  // NBLK == 256
    int k = blockIdx.x;
    int v = gcnt[b * NB + k];
    col[b] = v;
    __syncthreads();
    for (int o = 1; o < 256; o <<= 1) {
        int t = (b >= o) ? col[b - o] : 0;
        __syncthreads();
        col[b] += t;
        __syncthreads();
    }
    gcnt[b * NB + k] = bstart[k] + col[b] - v;
}

// ---------------- pass 3: scatter edges into bucket-grouped ebuf ----------------
// packed: src (17 bits) | (dst & 511) << 17
__global__ __launch_bounds__(256) void k_b3(const int* __restrict__ edge, int E, int chunk,
                                            int NB, const int* __restrict__ base,
                                            int* __restrict__ ebuf) {
    __shared__ int cnt[512];
    __shared__ int bs[512];
    int tid = threadIdx.x;
    for (int i = tid; i < NB; i += 256) {
        cnt[i] = 0;
        bs[i] = base[blockIdx.x * NB + i];
    }
    __syncthreads();
    int s = blockIdx.x * chunk, e = min(s + chunk, E);
    for (int i = s + tid; i < e; i += 256) {
        int sv = edge[i], dv = edge[E + i];
        int k = dv >> 9;
        int r = atomicAdd(&cnt[k], 1);  // LDS atomic
        ebuf[bs[k] + r] = sv | ((dv & 511) << 17);
    }
}

// ---------------- pass 4+5 merged: per-bucket hist + local scan -> off, dinv, ws ----------------
// off[node] = bstart[bucket] + exclusive_scan_within_bucket(deg); ws = dinv*scale
__global__ __launch_bounds__(256) void k_b45(const int* __restrict__ ebuf,
                                             const int* __restrict__ bstart,
                                             const float* __restrict__ scale, int n, int E,
                                             int NB, int* __restrict__ off,
                                             float* __restrict__ dinv,
                                             float* __restrict__ ws) {
    __shared__ int cnt[512];
    __shared__ int red[256];
    int tid = threadIdx.x;
    int k = blockIdx.x;
    cnt[tid] = 0;
    cnt[tid + 256] = 0;
    __syncthreads();
    int s = bstart[k], e = bstart[k + 1];
    for (int i = s + tid; i < e; i += 256) atomicAdd(&cnt[(ebuf[i] >> 17) & 511], 1);
    __syncthreads();
    int c0 = cnt[tid * 2], c1 = cnt[tid * 2 + 1];
    int sum = c0 + c1;
    red[tid] = sum;
    __syncthreads();
    for (int o = 1; o < 256; o <<= 1) {
        int v = (tid >= o) ? red[tid - o] : 0;
        __syncthreads();
        red[tid] += v;
        __syncthreads();
    }
    int ex = red[tid] - sum;  // exclusive prefix over pairs
    int base = k << 9;
    int g0 = base + tid * 2, g1 = g0 + 1;
    int o0 = s + ex, o1 = s + ex + c0;
    if (g0 < n) {
        off[g0] = o0;
        float d0 = rsqrtf((float)(c0 + 1));
        dinv[g0] = d0;
        ws[g0] = d0 * scale[g0];
    } else if (g0 == n) off[g0] = o0;
    if (g1 < n) {
        off[g1] = o1;
        float d1 = rsqrtf((float)(c1 + 1));
        dinv[g1] = d1;
        ws[g1] = d1 * scale[g1];
    } else if (g1 == n) off[g1] = o1;
    if (k == NB - 1 && tid == 0) off[n] = E;
}

// ---------------- pass 6: per-bucket CSR fill (LDS ranks, LDS off) ----------------
// pair.y = ws[src] = dinv[src]*scale[src] (single 4B gather per edge)
__global__ __launch_bounds__(256) void k_b6(const int* __restrict__ ebuf,
                                            const int* __restrict__ bstart,
                                            const int* __restrict__ off,
                                            const float* __restrict__ ws, int n,
                                            int2* __restrict__ pair) {
    __shared__ int cnt[512];
    __shared__ int offl[512];
    int tid = threadIdx.x;
    int k = blockIdx.x;
    int base = k << 9;
    cnt[tid] = 0;
    cnt[tid + 256] = 0;
    offl[tid] = (base + tid < n) ? off[base + tid] : 0;
    offl[tid + 256] = (base + 256 + tid < n) ? off[base + 256 + tid] : 0;
    __syncthreads();
    int s = bstart[k], e = bstart[k + 1];
    for (int i = s + tid; i < e; i += 256) {
        int pk = ebuf[i];
        int sv = pk & 0x1ffff;
        int node = (pk >> 17) & 511;
        int r = atomicAdd(&cnt[node], 1);  // LDS atomic
        pair[offl[node] + r] = make_int2(sv, __float_as_int(ws[sv]));
    }
}

// ---------------- x -> per-row-scaled biased-u8 (one wave per row) ----------------
// stored byte = round(x*127/max)+128  (unsigned, so agg converts via v_cvt_f32_ubyteN)
__global__ __launch_bounds__(256) void k_quant(const float* __restrict__ x,
                                               unsigned char* __restrict__ xq,
                                               float* __restrict__ scale, int n) {
    int row = blockIdx.x * 4 + (threadIdx.x >> 6);
    int lane = threadIdx.x & 63;
    if (row >= n) return;
    f32x4 v = ((const f32x4*)x)[(size_t)row * 64 + lane];
    float m = fmaxf(fmaxf(fabsf(v[0]), fabsf(v[1])), fmaxf(fabsf(v[2]), fabsf(v[3])));
    for (int o = 32; o > 0; o >>= 1) m = fmaxf(m, __shfl_xor(m, o));
    m = fmaxf(m, 1e-20f);
    float inv = 127.0f / m;
    int b0 = (__float2int_rn(v[0] * inv) + 128) & 255;
    int b1 = (__float2int_rn(v[1] * inv) + 128) & 255;
    int b2 = (__float2int_rn(v[2] * inv) + 128) & 255;
    int b3 = (__float2int_rn(v[3] * inv) + 128) & 255;
    ((int*)xq)[(size_t)row * 64 + lane] = b0 | (b1 << 8) | (b2 << 16) | (b3 << 24);
    if (lane == 0) scale[row] = m / 127.0f;
}

// ---------------- tb (n x 64 bf16) -> per-row biased-u8 + scale + r2 ----------------
__global__ __launch_bounds__(256) void k_quant2(const bf16* __restrict__ tb,
                                                const float* __restrict__ scale,
                                                unsigned char* __restrict__ tq,
                                                float* __restrict__ tscale,
                                                float* __restrict__ r2, int n) {
    int t = blockIdx.x * 256 + threadIdx.x;
    int row = t >> 3;
    int l8 = t & 7;
    if (row >= n) return;
    bf16x8 v = ((const bf16x8*)tb)[(size_t)row * 8 + l8];
    float f[8], m = 0.0f;
#pragma unroll
    for (int j = 0; j < 8; ++j) { f[j] = (float)v[j]; m = fmaxf(m, fabsf(f[j])); }
    for (int o = 4; o > 0; o >>= 1) m = fmaxf(m, __shfl_xor(m, o));
    m = fmaxf(m, 1e-20f);
    float inv = 127.0f / m;
    int lo = 0, hi = 0;
#pragma unroll
    for (int j = 0; j < 4; ++j) lo |= ((__float2int_rn(f[j] * inv) + 128) & 255) << (8 * j);
#pragma unroll
    for (int j = 0; j < 4; ++j) hi |= ((__float2int_rn(f[4 + j] * inv) + 128) & 255) << (8 * j);
    ((int2*)tq)[(size_t)row * 8 + l8] = make_int2(lo, hi);
    if (l8 == 0) {
        float s = m / 127.0f;
        tscale[row] = s;
        r2[row] = s / scale[row];  // pair.y * r2[src] == dinv[src]*tscale[src]
    }
}

// ---------------- W (KxNC fp32) -> Wt (NCxK bf16) ----------------
__global__ void k_wt(const float* __restrict__ W, bf16* __restrict__ Wt, int NC) {
    int nc = blockIdx.x;
    int k = threadIdx.x;
    Wt[nc * 256 + k] = (bf16)W[k * NC + nc];
}

// accumulate 16 biased-u8 elements: a[j] += w*u[j]; wsum += w
// (float)((u>>8)&255) etc. lower to single v_cvt_f32_ubyte{0..3}
__device__ __forceinline__ void acc16(float a[16], uint4 t, float w, float& wsum) {
    wsum += w;
    unsigned u0 = t.x, u1 = t.y, u2 = t.z, u3 = t.w;
    a[0]  += w * (float)(u0 & 255u);
    a[1]  += w * (float)((u0 >> 8) & 255u);
    a[2]  += w * (float)((u0 >> 16) & 255u);
    a[3]  += w * (float)(u0 >> 24);
    a[4]  += w * (float)(u1 & 255u);
    a[5]  += w * (float)((u1 >> 8) & 255u);
    a[6]  += w * (float)((u1 >> 16) & 255u);
    a[7]  += w * (float)(u1 >> 24);
    a[8]  += w * (float)(u2 & 255u);
    a[9]  += w * (float)((u2 >> 8) & 255u);
    a[10] += w * (float)((u2 >> 16) & 255u);
    a[11] += w * (float)(u2 >> 24);
    a[12] += w * (float)(u3 & 255u);
    a[13] += w * (float)((u3 >> 8) & 255u);
    a[14] += w * (float)((u3 >> 16) & 255u);
    a[15] += w * (float)(u3 >> 24);
}

// accumulate 8 biased-u8 elements from int2
__device__ __forceinline__ void acc8(float a[8], int2 t, float w, float& wsum) {
    wsum += w;
    unsigned u0 = (unsigned)t.x, u1 = (unsigned)t.y;
    a[0] += w * (float)(u0 & 255u);
    a[1] += w * (float)((u0 >> 8) & 255u);
    a[2] += w * (float)((u0 >> 16) & 255u);
    a[3] += w * (float)(u0 >> 24);
    a[4] += w * (float)(u1 & 255u);
    a[5] += w * (float)((u1 >> 8) & 255u);
    a[6] += w * (float)((u1 >> 16) & 255u);
    a[7] += w * (float)(u1 >> 24);
}

// ---------------- agg1: ax = A @ x. 4 nodes/wave, 16 lanes/node, 16B/lane ----------------
// Software-rotated: next iteration's pairs load while current gathers/FMAs run.
__global__ __launch_bounds__(256) void k_agg1(const unsigned char* __restrict__ xq,
                                              const float* __restrict__ scale,
                                              const int* __restrict__ off,
                                              const int2* __restrict__ pair,
                                              const float* __restrict__ dinv,
                                              bf16* __restrict__ ax, int n) {
    int wv = blockIdx.x * 4 + (threadIdx.x >> 6);
    int lane = threadIdx.x & 63;
    int node = wv * 4 + (lane >> 4);
    int l16 = lane & 15;
    if (node >= n) return;
    int s0 = off[node], s1 = off[node + 1];
    float dv = dinv[node];
    float a[16] = {};
    float wsum = 0.0f;
    uint4 xs = *(const uint4*)(xq + (size_t)node * 256 + l16 * 16);
    acc16(a, xs, dv * scale[node], wsum);  // self loop
    int e = s0;
    if (s1 - s0 >= 4) {
        int2 p[4];
#pragma unroll
        for (int q = 0; q < 4; ++q) p[q] = pair[s0 + q];
        e = s0 + 4;
        for (; e + 4 <= s1; e += 4) {
            uint4 t[4];
#pragma unroll
            for (int q = 0; q < 4; ++q)
                t[q] = *(const uint4*)(xq + (size_t)p[q].x * 256 + l16 * 16);
            int2 pn[4];
#pragma unroll
            for (int q = 0; q < 4; ++q) pn[q] = pair[e + q];
#pragma unroll
            for (int q = 0; q < 4; ++q) acc16(a, t[q], __int_as_float(p[q].y), wsum);
#pragma unroll
            for (int q = 0; q < 4; ++q) p[q] = pn[q];
        }
        // drain the prefetched 4
        uint4 t[4];
#pragma unroll
        for (int q = 0; q < 4; ++q)
            t[q] = *(const uint4*)(xq + (size_t)p[q].x * 256 + l16 * 16);
#pragma unroll
        for (int q = 0; q < 4; ++q) acc16(a, t[q], __int_as_float(p[q].y), wsum);
    }
    for (; e < s1; ++e) {
        int2 p = pair[e];
        uint4 t = *(const uint4*)(xq + (size_t)p.x * 256 + l16 * 16);
        acc16(a, t, __int_as_float(p.y), wsum);
    }
    float c = 128.0f * wsum;  // undo the +128 bias
    bf16x8 o0, o1;
#pragma unroll
    for (int j = 0; j < 8; ++j) o0[j] = (bf16)((a[j] - c) * dv);
#pragma unroll
    for (int j = 0; j < 8; ++j) o1[j] = (bf16)((a[8 + j] - c) * dv);
    ((bf16x8*)ax)[(size_t)node * 32 + l16 * 2] = o0;
    ((bf16x8*)ax)[(size_t)node * 32 + l16 * 2 + 1] = o1;
}

// LDS slot swizzle (slot in 16B units): spreads lane-stride-16B reads across banks.
__device__ __forceinline__ int swz(int s) { return s ^ ((s >> 3) & 7); }

// ---------------- row-panel GEMM (layer 1): C[n x 256] = A[n x 256] @ Bt^T, +bias+relu ----
// 64-row panel per block; A read once; XOR-swizzled LDS (conflict-free b128 reads).
__global__ __launch_bounds__(256) void k_gemmp(const bf16* __restrict__ A,
                                               const bf16* __restrict__ Bt,
                                               const float* __restrict__ bias,
                                               bf16* __restrict__ C, int n) {
    __shared__ __align__(16) bf16 As[4 * 64 * 8];    // 64 rows x 32 k
    __shared__ __align__(16) bf16 Bs[16 * 64 * 8];   // 256 N x 32 k
    int tid = threadIdx.x;
    int bm = blockIdx.x * 64;
    int w = tid >> 6, lane = tid & 63;

    int r = tid >> 2;
    int cq = tid & 3;
    int a_slot = swz(((r >> 4) * 64) + cq * 16 + (r & 15));
    int arow = bm + r; if (arow > n - 1) arow = n - 1;

    f32x4 acc[16] = {};

    for (int k0 = 0; k0 < 256; k0 += 32) {
        __syncthreads();
        uint4 av = *(const uint4*)(A + (size_t)arow * 256 + k0 + cq * 8);
        *(uint4*)(As + a_slot * 8) = av;
#pragma unroll
        for (int rep = 0; rep < 4; ++rep) {
            int r2 = rep * 64 + r;
            uint4 bv = *(const uint4*)(Bt + (size_t)r2 * 256 + k0 + cq * 8);
            *(uint4*)(Bs + swz(((r2 >> 4) * 64) + cq * 16 + (r2 & 15)) * 8) = bv;
        }
        __syncthreads();
        bf16x8 af = *(const bf16x8*)(As + swz(w * 64 + lane) * 8);
#pragma unroll
        for (int ct = 0; ct < 16; ++ct) {
            bf16x8 bfr = *(const bf16x8*)(Bs + swz(ct * 64 + lane) * 8);
            acc[ct] = __builtin_amdgcn_mfma_f32_16x16x32_bf16(af, bfr, acc[ct], 0, 0, 0);
        }
    }

    int colb = lane & 15, rowq = lane >> 4;
#pragma unroll
    for (int ct = 0; ct < 16; ++ct) {
        int col = ct * 16 + colb;
        float bv = bias[col];
#pragma unroll
        for (int rr = 0; rr < 4; ++rr) {
            int row = bm + w * 16 + rowq * 4 + rr;
            if (row < n) {
                float v = acc[ct][rr] + bv;
                C[(size_t)row * 256 + col] = (bf16)(v > 0.0f ? v : 0.0f);
            }
        }
    }
}

// ---------------- 64x64 GEMM (layer 2): C[n x 64] = A[n x 256] @ Bt[64 x 256]^T ----------------
__global__ __launch_bounds__(256) void k_gemm2(const bf16* __restrict__ A,
                                               const bf16* __restrict__ Bt,
                                               bf16* __restrict__ C, int n) {
    __shared__ __align__(16) bf16 As[4 * 64 * 8];
    __shared__ __align__(16) bf16 Bs[4 * 64 * 8];
    int tid = threadIdx.x;
    int bm = blockIdx.x * 64;
    int w = tid >> 6, lane = tid & 63;
    int wm = w >> 1, wn = w & 1;

    int r = tid >> 2;
    int cq = tid & 3;
    int lds_slot = swz(((r >> 4) * 64) + cq * 16 + (r & 15));
    int arow = bm + r; if (arow > n - 1) arow = n - 1;

    f32x4 acc[2][2] = {};

    for (int k0 = 0; k0 < 256; k0 += 32) {
        __syncthreads();
        uint4 av = *(const uint4*)(A + (size_t)arow * 256 + k0 + cq * 8);
        uint4 bv = *(const uint4*)(Bt + (size_t)r * 256 + k0 + cq * 8);
        *(uint4*)(As + lds_slot * 8) = av;
        *(uint4*)(Bs + lds_slot * 8) = bv;
        __syncthreads();
#pragma unroll
        for (int i = 0; i < 2; ++i) {
            bf16x8 af = *(const bf16x8*)(As + swz((wm * 2 + i) * 64 + lane) * 8);
#pragma unroll
            for (int j = 0; j < 2; ++j) {
                bf16x8 bfr = *(const bf16x8*)(Bs + swz((wn * 2 + j) * 64 + lane) * 8);
                acc[i][j] = __builtin_amdgcn_mfma_f32_16x16x32_bf16(af, bfr, acc[i][j], 0, 0, 0);
            }
        }
    }

    int colb = lane & 15, rowq = lane >> 4;
#pragma unroll
    for (int i = 0; i < 2; ++i) {
#pragma unroll
        for (int j = 0; j < 2; ++j) {
            int col = wn * 32 + j * 16 + colb;
#pragma unroll
            for (int rr = 0; rr < 4; ++rr) {
                int row = bm + wm * 32 + i * 16 + rowq * 4 + rr;
                if (row < n) C[(size_t)row * 64 + col] = (bf16)acc[i][j][rr];
            }
        }
    }
}

// ---------------- agg2 + bias + log_softmax. 8 nodes/wave, 8 lanes/node ----------------
// per-edge weight = pair.y * r2[src] == dinv[src]*tscale[src]; rotated prefetch.
__global__ __launch_bounds__(256) void k_agg2(const unsigned char* __restrict__ tq,
                                              const float* __restrict__ tscale,
                                              const float* __restrict__ r2,
                                              const int* __restrict__ off,
                                              const int2* __restrict__ pair,
                                              const float* __restrict__ dinv,
                                              const float* __restrict__ b2,
                                              float* __restrict__ out, int n) {
    int wv = blockIdx.x * 4 + (threadIdx.x >> 6);
    int lane = threadIdx.x & 63;
    int node = wv * 8 + (lane >> 3);
    int l8 = lane & 7;
    if (node >= n) return;
    int s0 = off[node], s1 = off[node + 1];
    float dv = dinv[node];
    const int2* T = (const int2*)tq;  // row = 8 x int2 (64B)
    int2 ts = T[(size_t)node * 8 + l8];
    float a[8] = {};
    float wsum = 0.0f;
    acc8(a, ts, dv * tscale[node], wsum);  // self loop
    int e = s0;
    if (s1 - s0 >= 4) {
        int2 p[4]; float sc[4];
#pragma unroll
        for (int q = 0; q < 4; ++q) p[q] = pair[s0 + q];
#pragma unroll
        for (int q = 0; q < 4; ++q) sc[q] = r2[p[q].x];
        e = s0 + 4;
        for (; e + 4 <= s1; e += 4) {
            int2 t[4];
#pragma unroll
            for (int q = 0; q < 4; ++q) t[q] = T[(size_t)p[q].x * 8 + l8];
            int2 pn[4];
#pragma unroll
            for (int q = 0; q < 4; ++q) pn[q] = pair[e + q];
            float scn[4];
#pragma unroll
            for (int q = 0; q < 4; ++q) scn[q] = r2[pn[q].x];
#pragma unroll
            for (int q = 0; q < 4; ++q) acc8(a, t[q], __int_as_float(p[q].y) * sc[q], wsum);
#pragma unroll
            for (int q = 0; q < 4; ++q) { p[q] = pn[q]; sc[q] = scn[q]; }
        }
        int2 t[4];
#pragma unroll
        for (int q = 0; q < 4; ++q) t[q] = T[(size_t)p[q].x * 8 + l8];
#pragma unroll
        for (int q = 0; q < 4; ++q) acc8(a, t[q], __int_as_float(p[q].y) * sc[q], wsum);
    }
    for (; e < s1; ++e) {
        int2 p = pair[e];
        float w = __int_as_float(p.y) * r2[p.x];
        int2 t = T[(size_t)p.x * 8 + l8];
        acc8(a, t, w, wsum);
    }
    float c = 128.0f * wsum;  // undo the +128 bias
    const float4* B2 = (const float4*)b2;
    float4 bv0 = B2[l8 * 2], bv1 = B2[l8 * 2 + 1];
    a[0] = (a[0] - c) * dv + bv0.x; a[1] = (a[1] - c) * dv + bv0.y;
    a[2] = (a[2] - c) * dv + bv0.z; a[3] = (a[3] - c) * dv + bv0.w;
    a[4] = (a[4] - c) * dv + bv1.x; a[5] = (a[5] - c) * dv + bv1.y;
    a[6] = (a[6] - c) * dv + bv1.z; a[7] = (a[7] - c) * dv + bv1.w;
    float m = a[0];
#pragma unroll
    for (int j = 1; j < 8; ++j) m = fmaxf(m, a[j]);
    for (int o = 4; o > 0; o >>= 1) m = fmaxf(m, __shfl_xor(m, o));
    float s = 0.0f;
#pragma unroll
    for (int j = 0; j < 8; ++j) s += __expf(a[j] - m);
    for (int o = 4; o > 0; o >>= 1) s += __shfl_xor(s, o);
    float ls = m + __logf(s);
    f32x4 o0, o1;
    o0[0] = a[0] - ls; o0[1] = a[1] - ls; o0[2] = a[2] - ls; o0[3] = a[3] - ls;
    o1[0] = a[4] - ls; o1[1] = a[5] - ls; o1[2] = a[6] - ls; o1[3] = a[7] - ls;
    f32x4* O = (f32x4*)out;  // row = 16 x f32x4
    O[(size_t)node * 16 + l8 * 2] = o0;
    O[(size_t)node * 16 + l8 * 2 + 1] = o1;
}

extern "C" void kernel_launch(void* const* d_in, const int* in_sizes, int n_in,
                              void* d_out, int out_size, void* d_ws, size_t ws_size,
                              hipStream_t stream) {
    const float* x   = (const float*)d_in[0];
    const int*  edge = (const int*)d_in[1];
    const float* W1  = (const float*)d_in[2];
    const float* b1  = (const float*)d_in[3];
    const float* W2  = (const float*)d_in[4];
    const float* b2  = (const float*)d_in[5];
    float* out = (float*)d_out;

    int n = in_sizes[0] / 256;   // 100000
    int E = in_sizes[1] / 2;     // 3200000
    int NB = (n + 511) >> 9;     // node buckets (512 each); requires n < 131072
    int chunk = (E + NBLK - 1) / NBLK;

    char* ws = (char*)d_ws;
    auto alloc = [&](size_t bytes) -> char* {
        char* p = ws;
        ws += (bytes + 255) & ~(size_t)255;
        return p;
    };
    int*   gcnt   = (int*)alloc((size_t)NBLK * NB * 4);
    int*   bstart = (int*)alloc((size_t)(NB + 1) * 4);
    int*   ebuf   = (int*)alloc((size_t)E * 4);
    float* dinv   = (float*)alloc((size_t)n * 4);
    float* wsv    = (float*)alloc((size_t)n * 4);
    int*   off    = (int*)alloc((size_t)(n + 1) * 4);
    int2*  pair   = (int2*)alloc((size_t)E * 8);
    unsigned char* xq = (unsigned char*)alloc((size_t)n * 256);
    float* scale  = (float*)alloc((size_t)n * 4);
    bf16*  ax     = (bf16*)alloc((size_t)n * 256 * 2);
    bf16*  h1     = (bf16*)alloc((size_t)n * 256 * 2);
    bf16*  tb     = (bf16*)alloc((size_t)n * 64 * 2);
    unsigned char* tq = (unsigned char*)alloc((size_t)n * 64);
    float* tscale = (float*)alloc((size_t)n * 4);
    float* r2     = (float*)alloc((size_t)n * 4);
    bf16*  W1t    = (bf16*)alloc(256 * 256 * 2);
    bf16*  W2t    = (bf16*)alloc(64 * 256 * 2);

    // --- feature quant first (k_b45 folds scale into ws = dinv*scale) ---
    k_quant<<<(n + 3) / 4, 256, 0, stream>>>(x, xq, scale, n);

    // --- CSR build (no global atomics) ---
    k_b1<<<NBLK, 256, 0, stream>>>(edge, E, chunk, NB, gcnt);
    k_b2<<<1, 256, 0, stream>>>(gcnt, NB, E, bstart);
    k_b2b<<<NB, 256, 0, stream>>>(gcnt, NB, bstart);
    k_b3<<<NBLK, 256, 0, stream>>>(edge, E, chunk, NB, gcnt, ebuf);
    k_b45<<<NB, 256, 0, stream>>>(ebuf, bstart, scale, n, E, NB, off, dinv, wsv);
    k_b6<<<NB, 256, 0, stream>>>(ebuf, bstart, off, wsv, n, pair);

    // --- weights ---
    k_wt<<<256, 256, 0, stream>>>(W1, W1t, 256);
    k_wt<<<64, 256, 0, stream>>>(W2, W2t, 64);

    // --- layer 1 ---
    k_agg1<<<(n + 15) / 16, 256, 0, stream>>>(xq, scale, off, pair, dinv, ax, n);
    k_gemmp<<<(n + 63) / 64, 256, 0, stream>>>(ax, W1t, b1, h1, n);

    // --- layer 2 ---
    k_gemm2<<<(n + 63) / 64, 256, 0, stream>>>(h1, W2t, tb, n);
    k_quant2<<<(n * 8 + 255) / 256, 256, 0, stream>>>(tb, scale, tq, tscale, r2, n);
    k_agg2<<<(n + 31) / 32, 256, 0, stream>>>(tq, tscale, r2, off, pair, dinv, b2, out, n);
}